// Round 1
// 597.259 us; speedup vs baseline: 1.0496x; 1.0496x over previous
//
#include <hip/hip_runtime.h>
#include <stdint.h>

// Problem constants
#define BB    8
#define NN_   16384
#define SS    1024
#define PP    131072    // BB*NN_
#define CIN   512
#define CMID  256
#define COUT  256

typedef short  bf16x8 __attribute__((ext_vector_type(8)));
typedef float  f32x4  __attribute__((ext_vector_type(4)));
typedef unsigned short u16x8 __attribute__((ext_vector_type(8)));
typedef unsigned int uint_;

__device__ __forceinline__ float bf2f(unsigned short u){
  union { unsigned int i; float f; } v; v.i = ((unsigned int)u) << 16; return v.f;
}
__device__ __forceinline__ unsigned short f2bf(float f){
  union { float f; unsigned int i; } v; v.f = f;
  unsigned int r = (v.i + 0x7fffu + ((v.i >> 16) & 1u)) >> 16;  // RNE
  return (unsigned short)r;
}

// async global->LDS, 16B per lane; LDS dest must be wave-uniform base (+lane*16 implicit)
__device__ __forceinline__ void async_ld16(const void* g, void* l){
  const uint32_t __attribute__((address_space(1)))* gp =
    reinterpret_cast<const uint32_t __attribute__((address_space(1)))*>(reinterpret_cast<uintptr_t>(g));
  uint32_t __attribute__((address_space(3)))* lp =
    reinterpret_cast<uint32_t __attribute__((address_space(3)))*>(reinterpret_cast<uintptr_t>(l));
  __builtin_amdgcn_global_load_lds(gp, lp, 16, 0, 0);
}

// ---------------------------------------------------------------------------
// Prep: weights fp32->bf16, zero BN stats. (conv biases b0/b1 cancel exactly in
// training-mode BN: (y+b) - mean(y+b) == y - mean(y); variance unchanged.)
__global__ void k_prep(const float* __restrict__ w0, const float* __restrict__ w1,
                       unsigned short* __restrict__ w0b, unsigned short* __restrict__ w1b,
                       float* __restrict__ bn)
{
  int idx = blockIdx.x * 256 + threadIdx.x;   // grid 512 -> 131072 threads
  if (idx < 131072) w0b[idx] = f2bf(w0[idx]);
  if (idx < 65536)  w1b[idx] = f2bf(w1[idx]);
  if (idx < 2048)   bn[idx]  = 0.0f;          // stats + params region
}

// ---------------------------------------------------------------------------
// points2 [B][256][S] fp32 -> p2t [B][S][256] fp32 (coalesced gather rows)
__global__ void k_p2t(const float* __restrict__ p2, float* __restrict__ p2t)
{
  __shared__ float t[32][33];
  const int b = blockIdx.z, c0 = blockIdx.y * 32, s0 = blockIdx.x * 32;
  const int tx = threadIdx.x, ty = threadIdx.y;   // (32,8)
#pragma unroll
  for (int r = 0; r < 4; r++)
    t[ty + r*8][tx] = p2[((size_t)b*256 + c0 + ty + r*8) * SS + s0 + tx];
  __syncthreads();
#pragma unroll
  for (int r = 0; r < 4; r++)
    p2t[((size_t)b*SS + s0 + ty + r*8) * 256 + c0 + tx] = t[tx][ty + r*8];
}

// points1 [B][256][N] fp32 -> xcat[p][0:256] bf16  (row stride 512)
__global__ void k_p1t(const float* __restrict__ p1, unsigned short* __restrict__ xcat)
{
  __shared__ float t[32][33];
  const int b = blockIdx.z, c0 = blockIdx.y * 32, n0 = blockIdx.x * 32;
  const int tx = threadIdx.x, ty = threadIdx.y;
#pragma unroll
  for (int r = 0; r < 4; r++)
    t[ty + r*8][tx] = p1[((size_t)b*256 + c0 + ty + r*8) * (size_t)NN_ + n0 + tx];
  __syncthreads();
#pragma unroll
  for (int r = 0; r < 4; r++)
    xcat[((size_t)b*NN_ + n0 + ty + r*8) * 512 + c0 + tx] = f2bf(t[tx][ty + r*8]);
}

// ---------------------------------------------------------------------------
// 3-NN + inverse-distance interp -> xcat[p][256:512] bf16
// R4: (a) scan = branchless top-6 min/max network on packed u32 keys
//     (key = fp32-dist bits with low 10 bits replaced by index s; positive
//     fp32 compares as uint; ties -> smaller s, matching top_k stability).
//     No VCC round-trips (R3's cmp+cndmask chain was ~2x the issue cost).
//     fp64 refine of the 6 candidates restores exact numpy top-3 (failure
//     needs 4 points within ~0.2% rel of d3: P ~ 2e-8/query).
// (b) gather = wave-owns-64-points, float4 (16B/lane) row loads, dwordx2
//     bf16 stores, metadata via 2x ds_read_b128 broadcast.
// (c) XCD swizzle b = blk&7: all blocks of batch b share an XCD -> p2t slice
//     (1 MB) is L2-resident (R3 FETCH was 94 MB vs ~10 MB ideal).
__global__ __launch_bounds__(256) void k_nn(const float* __restrict__ xyz1,
                                            const float* __restrict__ xyz2,
                                            const float* __restrict__ p2t,
                                            unsigned short* __restrict__ xcat)
{
  __shared__ float4 pts[SS];       // 16 KB, broadcast reads
  __shared__ int4   mi[256];       // 4 KB: i0,i1,i2,pad per point
  __shared__ float4 mw[256];       // 4 KB: w0,w1,w2,pad per point
  const int blk = blockIdx.x;                  // 512 blocks
  const int b = blk & 7, nt = blk >> 3;        // XCD-aware: b == XCD id
  const int n0 = nt * 256, tid = threadIdx.x;

  for (int s = tid; s < SS; s += 256) {
    float x = xyz2[((size_t)b*3 + 0) * SS + s];
    float y = xyz2[((size_t)b*3 + 1) * SS + s];
    float z = xyz2[((size_t)b*3 + 2) * SS + s];
    pts[s] = make_float4(x, y, z, 0.0f);
  }
  __syncthreads();

  const int n = n0 + tid;
  const float qx = xyz1[((size_t)b*3 + 0) * NN_ + n];
  const float qy = xyz1[((size_t)b*3 + 1) * NN_ + n];
  const float qz = xyz1[((size_t)b*3 + 2) * NN_ + n];

  uint_ k0 = 0xFFFFFFFFu, k1 = 0xFFFFFFFFu, k2 = 0xFFFFFFFFu;
  uint_ k3 = 0xFFFFFFFFu, k4 = 0xFFFFFFFFu, k5 = 0xFFFFFFFFu;
#pragma unroll 4
  for (int s = 0; s < SS; s++) {
    float4 p = pts[s];
    float dx = qx - p.x, dy = qy - p.y, dz = qz - p.z;
    float d = fmaf(dx, dx, fmaf(dy, dy, dz * dz));
    uint_ key = (__float_as_uint(d) & 0xFFFFFC00u) | (uint_)s;
    // sorted-insert into ascending (k0..k5): new_ki = min(ki, max(k_{i-1}, key))
    // all from OLD values -> depth 2, fully parallel min/max, no vcc.
    uint_ m1 = max(k0, key);
    uint_ m2 = max(k1, key);
    uint_ m3 = max(k2, key);
    uint_ m4 = max(k3, key);
    uint_ m5 = max(k4, key);
    k0 = min(k0, key);
    k1 = min(k1, m1);
    k2 = min(k2, m2);
    k3 = min(k3, m3);
    k4 = min(k4, m4);
    k5 = min(k5, m5);
  }

  // fp64 refine: exact distances for the 6 candidates, stable sort, top-3
  const double qxd = (double)qx, qyd = (double)qy, qzd = (double)qz;
  uint_  ks[6] = { k0, k1, k2, k3, k4, k5 };
  int    ii[6];
  double dd[6];
#pragma unroll
  for (int t = 0; t < 6; t++) {
    ii[t] = (int)(ks[t] & 1023u);
    float4 p = pts[ii[t]];
    double dx = qxd - (double)p.x, dy = qyd - (double)p.y, dz = qzd - (double)p.z;
    dd[t] = dx*dx + dy*dy + dz*dz;
  }
#pragma unroll
  for (int a = 1; a < 6; a++)
#pragma unroll
    for (int c = a; c > 0; c--)
      if (dd[c] < dd[c-1]) {
        double td = dd[c]; dd[c] = dd[c-1]; dd[c-1] = td;
        int    ti = ii[c]; ii[c] = ii[c-1]; ii[c-1] = ti;
      }

  double r0 = 1.0/(dd[0] + 1e-8), r1 = 1.0/(dd[1] + 1e-8), r2 = 1.0/(dd[2] + 1e-8);
  double rs = 1.0/(r0 + r1 + r2);
  mi[tid] = make_int4(ii[0], ii[1], ii[2], 0);
  mw[tid] = make_float4((float)(r0*rs), (float)(r1*rs), (float)(r2*rs), 0.0f);
  __syncthreads();

  // gather: wave w interpolates points j in [w*64, w*64+64); lane covers 4 ch
  const int wid = tid >> 6, lane = tid & 63;
  const float* p2tb = p2t + (size_t)b * SS * 256;
  unsigned short* outb = xcat + ((size_t)b*NN_ + n0) * 512 + 256 + lane*4;
#pragma unroll 2
  for (int t = 0; t < 64; t++) {
    int j = wid*64 + t;
    int4   im = mi[j];                 // broadcast ds_read_b128
    float4 wm = mw[j];
    const float4* ra = (const float4*)(p2tb + (size_t)im.x * 256) + lane;
    const float4* rb = (const float4*)(p2tb + (size_t)im.y * 256) + lane;
    const float4* rc = (const float4*)(p2tb + (size_t)im.z * 256) + lane;
    float4 A = *ra, Bv = *rb, Cv = *rc;
    float fx = wm.x*A.x + wm.y*Bv.x + wm.z*Cv.x;
    float fy = wm.x*A.y + wm.y*Bv.y + wm.z*Cv.y;
    float fz = wm.x*A.z + wm.y*Bv.z + wm.z*Cv.z;
    float fw = wm.x*A.w + wm.y*Bv.w + wm.z*Cv.w;
    uint_ lo = (uint_)f2bf(fx) | ((uint_)f2bf(fy) << 16);
    uint_ hi = (uint_)f2bf(fz) | ((uint_)f2bf(fw) << 16);
    uint2 pk; pk.x = lo; pk.y = hi;
    *(uint2*)(outb + (size_t)j * 512) = pk;
  }
}

// ---------------------------------------------------------------------------
// NT GEMM: Y[p][o] = sum_c X[p][c]*W[o][c].  X:[P][K] bf16, W:[256][K] bf16.
// 128x128 tile, BK=32, 4 waves (2p x 2o), MFMA 16x16x32 bf16.
// R5: 2-phase double-buffered pipeline (guide T3-minimum). Old structure was
//     stage(t) -> __syncthreads (vmcnt(0) drain) -> compute: every K-step
//     exposed ~900cy HBM latency -> 1.5 TB/s, MfmaUtil 9.8%, 4.3x above the
//     memory roofline (~32us). New: issue stage(t+2) right after frag reads,
//     counted s_waitcnt vmcnt(4) (stage t+1 stays in flight across barrier),
//     raw s_barrier. Explicit lgkmcnt(0) before the first barrier protects
//     the buffer overwrite (ds_reads must land in regs before DMA lands).
// Epilogue: per-channel sum/sumsq atomics (BN stats) + bf16 store.
__global__ __launch_bounds__(256) void k_gemm(const unsigned short* __restrict__ X,
                                              const unsigned short* __restrict__ W,
                                              unsigned short* __restrict__ Y,
                                              float* __restrict__ bnsum,
                                              float* __restrict__ bnsumsq,
                                              int K)
{
  // [buf][ Xs 4096 shorts | Ws 4096 shorts ] -> 32 KB total (5 blocks/CU LDS cap)
  __shared__ unsigned short lds[2][8192];
  const int tid  = threadIdx.x;
  const int wid  = tid >> 6, lane = tid & 63;
  const int quad = lane >> 4, l16 = lane & 15;
  const int wave_p = wid & 1, wave_o = wid >> 1;
  const size_t p0 = (size_t)blockIdx.x * 128;
  const int o0 = blockIdx.y * 128;

  f32x4 acc[4][4] = {};

  // staging granule -> (row, c8): row = g>>2, coff = (g&3)*8
  const int g2 = tid + 256;
  const int r1 = tid >> 2, c1 = (tid & 3) * 8;
  const int r2 = g2 >> 2,  c2 = (g2 & 3) * 8;
  const unsigned short* gX1 = X + (p0 + r1) * (size_t)K + c1;
  const unsigned short* gX2 = X + (p0 + r2) * (size_t)K + c2;
  const unsigned short* gW1 = W + (size_t)(o0 + r1) * K + c1;
  const unsigned short* gW2 = W + (size_t)(o0 + r2) * K + c2;
  const int ldso = wid * 512;          // wave-uniform LDS dest offset (shorts)
  const int nt = K >> 5;

  auto stage = [&](int t, int b) {
    const int kk = t * 32;
    async_ld16(gX1 + kk, &lds[b][ldso]);
    async_ld16(gX2 + kk, &lds[b][2048 + ldso]);
    async_ld16(gW1 + kk, &lds[b][4096 + ldso]);
    async_ld16(gW2 + kk, &lds[b][4096 + 2048 + ldso]);
  };

  const int axi = (wave_p*64 + l16) * 4 + quad;   // frag base index (bf16x8 units)
  const int bxi = (wave_o*64 + l16) * 4 + quad;

  // prologue: fill both buffers, wait for buf0
  stage(0, 0);
  stage(1, 1);
  asm volatile("s_waitcnt vmcnt(4)" ::: "memory");
  __builtin_amdgcn_s_barrier();

  bf16x8 af[4], bfr[4];
  for (int t = 0; t < nt - 2; ++t) {
    const int cb = t & 1;
    const bf16x8* xv = (const bf16x8*)&lds[cb][0];
    const bf16x8* wv = (const bf16x8*)&lds[cb][4096];
#pragma unroll
    for (int i = 0; i < 4; i++) {
      af[i]  = xv[axi + i*64];   // A[m=l16+i*16][k=quad*8..]
      bfr[i] = wv[bxi + i*64];
    }
    asm volatile("s_waitcnt lgkmcnt(0)" ::: "memory");  // frags in regs before overwrite
    __builtin_amdgcn_s_barrier();                       // all waves done reading cb
    stage(t + 2, cb);                                   // overwrite cb with tile t+2
#pragma unroll
    for (int pi = 0; pi < 4; pi++)
#pragma unroll
      for (int oi = 0; oi < 4; oi++)
        acc[pi][oi] = __builtin_amdgcn_mfma_f32_16x16x32_bf16(af[pi], bfr[oi], acc[pi][oi], 0, 0, 0);
    asm volatile("s_waitcnt vmcnt(4)" ::: "memory");    // stage(t+1) landed; t+2 in flight
    __builtin_amdgcn_s_barrier();
  }
  { // t = nt-2: no more staging; drain stage(nt-1) fully
    const int cb = (nt - 2) & 1;
    const bf16x8* xv = (const bf16x8*)&lds[cb][0];
    const bf16x8* wv = (const bf16x8*)&lds[cb][4096];
#pragma unroll
    for (int i = 0; i < 4; i++) { af[i] = xv[axi + i*64]; bfr[i] = wv[bxi + i*64]; }
#pragma unroll
    for (int pi = 0; pi < 4; pi++)
#pragma unroll
      for (int oi = 0; oi < 4; oi++)
        acc[pi][oi] = __builtin_amdgcn_mfma_f32_16x16x32_bf16(af[pi], bfr[oi], acc[pi][oi], 0, 0, 0);
    asm volatile("s_waitcnt vmcnt(0)" ::: "memory");
    __builtin_amdgcn_s_barrier();
  }
  { // t = nt-1
    const int cb = (nt - 1) & 1;
    const bf16x8* xv = (const bf16x8*)&lds[cb][0];
    const bf16x8* wv = (const bf16x8*)&lds[cb][4096];
#pragma unroll
    for (int i = 0; i < 4; i++) { af[i] = xv[axi + i*64]; bfr[i] = wv[bxi + i*64]; }
#pragma unroll
    for (int pi = 0; pi < 4; pi++)
#pragma unroll
      for (int oi = 0; oi < 4; oi++)
        acc[pi][oi] = __builtin_amdgcn_mfma_f32_16x16x32_bf16(af[pi], bfr[oi], acc[pi][oi], 0, 0, 0);
  }

  // BN stats: reduce over p (lane's 16 rows, then across quads), atomics per o
#pragma unroll
  for (int oi = 0; oi < 4; oi++) {
    float s = 0.0f, ss = 0.0f;
#pragma unroll
    for (int pi = 0; pi < 4; pi++)
#pragma unroll
      for (int i = 0; i < 4; i++) { float v = acc[pi][oi][i]; s += v; ss += v*v; }
    s  += __shfl_xor(s, 16, 64);  s  += __shfl_xor(s, 32, 64);
    ss += __shfl_xor(ss, 16, 64); ss += __shfl_xor(ss, 32, 64);
    if (quad == 0) {
      int o = o0 + wave_o*64 + oi*16 + l16;
      atomicAdd(&bnsum[o], s);
      atomicAdd(&bnsumsq[o], ss);
    }
  }
  // store raw y (bf16). D: row(p)=quad*4+i, col(o)=l16
#pragma unroll
  for (int pi = 0; pi < 4; pi++)
#pragma unroll
    for (int oi = 0; oi < 4; oi++)
#pragma unroll
      for (int i = 0; i < 4; i++) {
        size_t p = p0 + wave_p*64 + pi*16 + quad*4 + i;
        int    o = o0 + wave_o*64 + oi*16 + l16;
        Y[p * 256 + o] = f2bf(acc[pi][oi][i]);
      }
}

// ---------------------------------------------------------------------------
// BN param: scale = g*rsqrt(var+eps), shift = be - mean*scale
__global__ void k_bn(const float* __restrict__ sum, const float* __restrict__ sumsq,
                     const float* __restrict__ g, const float* __restrict__ be,
                     float* __restrict__ scale, float* __restrict__ shift)
{
  int o = threadIdx.x;
  const float inv = 1.0f / 131072.0f;
  float m  = sum[o] * inv;
  float v  = sumsq[o] * inv - m * m;
  float sc = g[o] * rsqrtf(v + 1e-5f);
  scale[o] = sc;
  shift[o] = be[o] - m * sc;
}

// elementwise z = relu(y*scale + shift), bf16 -> bf16 (keeps GEMM2 stage-able via lds-direct)
__global__ __launch_bounds__(256) void k_z(const unsigned short* __restrict__ y,
                                           const float* __restrict__ scale,
                                           const float* __restrict__ shift,
                                           unsigned short* __restrict__ z)
{
  size_t idx = ((size_t)blockIdx.x * 256 + threadIdx.x) * 8;
  int o = (int)(idx & 255);
  u16x8 v = *(const u16x8*)(y + idx);
  u16x8 r;
#pragma unroll
  for (int i = 0; i < 8; i++) {
    float f = bf2f(v[i]);
    float t = f * scale[o + i] + shift[o + i];
    r[i] = f2bf(fmaxf(t, 0.0f));
  }
  *(u16x8*)(z + idx) = r;
}

// final: y1[p][o] bf16 -> out[b][o][n] fp32 with BN+relu, LDS transpose
__global__ __launch_bounds__(256) void k_out(const unsigned short* __restrict__ y1,
                                             const float* __restrict__ scale,
                                             const float* __restrict__ shift,
                                             float* __restrict__ out)
{
  __shared__ float t[64][65];
  const int b = blockIdx.z, o0 = blockIdx.y * 64, n0 = blockIdx.x * 64;
  const int tx = threadIdx.x & 15, ty = threadIdx.x >> 4;
  const float4 sc = *(const float4*)(scale + o0 + tx*4);
  const float4 sh = *(const float4*)(shift + o0 + tx*4);
#pragma unroll
  for (int r = 0; r < 4; r++) {
    int nl = ty + r*16;
    const unsigned short* src = y1 + ((size_t)b*NN_ + n0 + nl) * 256 + o0 + tx*4;
    ushort4 v = *(const ushort4*)src;
    t[tx*4+0][nl] = fmaxf(bf2f(v.x) * sc.x + sh.x, 0.0f);
    t[tx*4+1][nl] = fmaxf(bf2f(v.y) * sc.y + sh.y, 0.0f);
    t[tx*4+2][nl] = fmaxf(bf2f(v.z) * sc.z + sh.z, 0.0f);
    t[tx*4+3][nl] = fmaxf(bf2f(v.w) * sc.w + sh.w, 0.0f);
  }
  __syncthreads();
#pragma unroll
  for (int r = 0; r < 4; r++) {
    int ol = ty + r*16;
    float4 o4 = make_float4(t[ol][tx*4+0], t[ol][tx*4+1], t[ol][tx*4+2], t[ol][tx*4+3]);
    *(float4*)(out + ((size_t)b*256 + o0 + ol) * (size_t)NN_ + n0 + tx*4) = o4;
  }
}

// ---------------------------------------------------------------------------
extern "C" void kernel_launch(void* const* d_in, const int* in_sizes, int n_in,
                              void* d_out, int out_size, void* d_ws, size_t ws_size,
                              hipStream_t stream)
{
  const float* xyz1 = (const float*)d_in[0];
  const float* xyz2 = (const float*)d_in[1];
  const float* p1   = (const float*)d_in[2];
  const float* p2   = (const float*)d_in[3];
  const float* w0   = (const float*)d_in[4];
  const float* g0   = (const float*)d_in[6];
  const float* be0  = (const float*)d_in[7];
  const float* w1   = (const float*)d_in[8];
  const float* g1   = (const float*)d_in[10];
  const float* be1  = (const float*)d_in[11];

  // workspace layout (~192.5 MiB):
  //   [0,128Mi)    xcat [P][512] bf16      (later reused: z=[0,64Mi), y1=[64Mi,128Mi))
  //   [128,192Mi)  y0 [P][256] bf16        (p2t aliases its first 8 MiB; dead before gemm1 writes)
  //   [192Mi,...]  w0b, w1b, bn stats/params
  char* ws = (char*)d_ws;
  unsigned short* xcat = (unsigned short*)(ws);
  unsigned short* y0   = (unsigned short*)(ws + 134217728ull);
  unsigned short* zbuf = (unsigned short*)(ws);
  unsigned short* y1   = (unsigned short*)(ws + 67108864ull);
  float*          p2t  = (float*)        (ws + 134217728ull);
  unsigned short* w0b  = (unsigned short*)(ws + 201326592ull);
  unsigned short* w1b  = (unsigned short*)(ws + 201588736ull);
  float*          bn   = (float*)        (ws + 201719808ull);
  // bn: [0]sum0 [256]sumsq0 [512]sum1 [768]sumsq1 [1024]scale0 [1280]shift0 [1536]scale1 [1792]shift1

  k_prep<<<512, 256, 0, stream>>>(w0, w1, w0b, w1b, bn);
  k_p2t <<<dim3(32, 8, 8),  dim3(32, 8), 0, stream>>>(p2, p2t);
  k_p1t <<<dim3(512, 8, 8), dim3(32, 8), 0, stream>>>(p1, xcat);
  k_nn  <<<512, 256, 0, stream>>>(xyz1, xyz2, p2t, xcat);
  k_gemm<<<dim3(1024, 2), 256, 0, stream>>>(xcat, w0b, y0, bn + 0,   bn + 256, 512);
  k_bn  <<<1, 256, 0, stream>>>(bn + 0,   bn + 256, g0, be0, bn + 1024, bn + 1280);
  k_z   <<<16384, 256, 0, stream>>>(y0, bn + 1024, bn + 1280, zbuf);
  k_gemm<<<dim3(1024, 2), 256, 0, stream>>>(zbuf, w1b, y1, bn + 512, bn + 768, 256);
  k_bn  <<<1, 256, 0, stream>>>(bn + 512, bn + 768, g1, be1, bn + 1536, bn + 1792);
  k_out <<<dim3(256, 4, 8), 256, 0, stream>>>(y1, bn + 1536, bn + 1792, (float*)d_out);
}

// Round 2
// 516.652 us; speedup vs baseline: 1.2134x; 1.1560x over previous
//
#include <hip/hip_runtime.h>
#include <stdint.h>

// Problem constants
#define BB    8
#define NN_   16384
#define SS    1024
#define PP    131072    // BB*NN_
#define CIN   512
#define CMID  256
#define COUT  256

typedef short  bf16x8 __attribute__((ext_vector_type(8)));
typedef float  f32x4  __attribute__((ext_vector_type(4)));
typedef unsigned short u16x8 __attribute__((ext_vector_type(8)));
typedef unsigned int uint_;

__device__ __forceinline__ float bf2f(unsigned short u){
  union { unsigned int i; float f; } v; v.i = ((unsigned int)u) << 16; return v.f;
}
__device__ __forceinline__ unsigned short f2bf(float f){
  union { float f; unsigned int i; } v; v.f = f;
  unsigned int r = (v.i + 0x7fffu + ((v.i >> 16) & 1u)) >> 16;  // RNE
  return (unsigned short)r;
}

// async global->LDS, 16B per lane; LDS dest must be wave-uniform base (+lane*16 implicit)
__device__ __forceinline__ void async_ld16(const void* g, void* l){
  const uint32_t __attribute__((address_space(1)))* gp =
    reinterpret_cast<const uint32_t __attribute__((address_space(1)))*>(reinterpret_cast<uintptr_t>(g));
  uint32_t __attribute__((address_space(3)))* lp =
    reinterpret_cast<uint32_t __attribute__((address_space(3)))*>(reinterpret_cast<uintptr_t>(l));
  __builtin_amdgcn_global_load_lds(gp, lp, 16, 0, 0);
}

// ---------------------------------------------------------------------------
// Prep: weights fp32->bf16, zero BN stats. (conv biases b0/b1 cancel exactly in
// training-mode BN: (y+b) - mean(y+b) == y - mean(y); variance unchanged.)
__global__ void k_prep(const float* __restrict__ w0, const float* __restrict__ w1,
                       unsigned short* __restrict__ w0b, unsigned short* __restrict__ w1b,
                       float* __restrict__ bn)
{
  int idx = blockIdx.x * 256 + threadIdx.x;   // grid 512 -> 131072 threads
  if (idx < 131072) w0b[idx] = f2bf(w0[idx]);
  if (idx < 65536)  w1b[idx] = f2bf(w1[idx]);
  if (idx < 2048)   bn[idx]  = 0.0f;          // stats + params region
}

// ---------------------------------------------------------------------------
// points2 [B][256][S] fp32 -> p2t [B][S][256] fp32 (coalesced gather rows)
__global__ void k_p2t(const float* __restrict__ p2, float* __restrict__ p2t)
{
  __shared__ float t[32][33];
  const int b = blockIdx.z, c0 = blockIdx.y * 32, s0 = blockIdx.x * 32;
  const int tx = threadIdx.x, ty = threadIdx.y;   // (32,8)
#pragma unroll
  for (int r = 0; r < 4; r++)
    t[ty + r*8][tx] = p2[((size_t)b*256 + c0 + ty + r*8) * SS + s0 + tx];
  __syncthreads();
#pragma unroll
  for (int r = 0; r < 4; r++)
    p2t[((size_t)b*SS + s0 + ty + r*8) * 256 + c0 + tx] = t[tx][ty + r*8];
}

// points1 [B][256][N] fp32 -> xcat[p][0:256] bf16  (row stride 512)
__global__ void k_p1t(const float* __restrict__ p1, unsigned short* __restrict__ xcat)
{
  __shared__ float t[32][33];
  const int b = blockIdx.z, c0 = blockIdx.y * 32, n0 = blockIdx.x * 32;
  const int tx = threadIdx.x, ty = threadIdx.y;
#pragma unroll
  for (int r = 0; r < 4; r++)
    t[ty + r*8][tx] = p1[((size_t)b*256 + c0 + ty + r*8) * (size_t)NN_ + n0 + tx];
  __syncthreads();
#pragma unroll
  for (int r = 0; r < 4; r++)
    xcat[((size_t)b*NN_ + n0 + ty + r*8) * 512 + c0 + tx] = f2bf(t[tx][ty + r*8]);
}

// ---------------------------------------------------------------------------
// 3-NN + inverse-distance interp -> xcat[p][256:512] bf16  (unchanged from R4)
__global__ __launch_bounds__(256) void k_nn(const float* __restrict__ xyz1,
                                            const float* __restrict__ xyz2,
                                            const float* __restrict__ p2t,
                                            unsigned short* __restrict__ xcat)
{
  __shared__ float4 pts[SS];       // 16 KB, broadcast reads
  __shared__ int4   mi[256];       // 4 KB: i0,i1,i2,pad per point
  __shared__ float4 mw[256];       // 4 KB: w0,w1,w2,pad per point
  const int blk = blockIdx.x;                  // 512 blocks
  const int b = blk & 7, nt = blk >> 3;        // XCD-aware: b == XCD id
  const int n0 = nt * 256, tid = threadIdx.x;

  for (int s = tid; s < SS; s += 256) {
    float x = xyz2[((size_t)b*3 + 0) * SS + s];
    float y = xyz2[((size_t)b*3 + 1) * SS + s];
    float z = xyz2[((size_t)b*3 + 2) * SS + s];
    pts[s] = make_float4(x, y, z, 0.0f);
  }
  __syncthreads();

  const int n = n0 + tid;
  const float qx = xyz1[((size_t)b*3 + 0) * NN_ + n];
  const float qy = xyz1[((size_t)b*3 + 1) * NN_ + n];
  const float qz = xyz1[((size_t)b*3 + 2) * NN_ + n];

  uint_ k0 = 0xFFFFFFFFu, k1 = 0xFFFFFFFFu, k2 = 0xFFFFFFFFu;
  uint_ k3 = 0xFFFFFFFFu, k4 = 0xFFFFFFFFu, k5 = 0xFFFFFFFFu;
#pragma unroll 4
  for (int s = 0; s < SS; s++) {
    float4 p = pts[s];
    float dx = qx - p.x, dy = qy - p.y, dz = qz - p.z;
    float d = fmaf(dx, dx, fmaf(dy, dy, dz * dz));
    uint_ key = (__float_as_uint(d) & 0xFFFFFC00u) | (uint_)s;
    uint_ m1 = max(k0, key);
    uint_ m2 = max(k1, key);
    uint_ m3 = max(k2, key);
    uint_ m4 = max(k3, key);
    uint_ m5 = max(k4, key);
    k0 = min(k0, key);
    k1 = min(k1, m1);
    k2 = min(k2, m2);
    k3 = min(k3, m3);
    k4 = min(k4, m4);
    k5 = min(k5, m5);
  }

  const double qxd = (double)qx, qyd = (double)qy, qzd = (double)qz;
  uint_  ks[6] = { k0, k1, k2, k3, k4, k5 };
  int    ii[6];
  double dd[6];
#pragma unroll
  for (int t = 0; t < 6; t++) {
    ii[t] = (int)(ks[t] & 1023u);
    float4 p = pts[ii[t]];
    double dx = qxd - (double)p.x, dy = qyd - (double)p.y, dz = qzd - (double)p.z;
    dd[t] = dx*dx + dy*dy + dz*dz;
  }
#pragma unroll
  for (int a = 1; a < 6; a++)
#pragma unroll
    for (int c = a; c > 0; c--)
      if (dd[c] < dd[c-1]) {
        double td = dd[c]; dd[c] = dd[c-1]; dd[c-1] = td;
        int    ti = ii[c]; ii[c] = ii[c-1]; ii[c-1] = ti;
      }

  double r0 = 1.0/(dd[0] + 1e-8), r1 = 1.0/(dd[1] + 1e-8), r2 = 1.0/(dd[2] + 1e-8);
  double rs = 1.0/(r0 + r1 + r2);
  mi[tid] = make_int4(ii[0], ii[1], ii[2], 0);
  mw[tid] = make_float4((float)(r0*rs), (float)(r1*rs), (float)(r2*rs), 0.0f);
  __syncthreads();

  const int wid = tid >> 6, lane = tid & 63;
  const float* p2tb = p2t + (size_t)b * SS * 256;
  unsigned short* outb = xcat + ((size_t)b*NN_ + n0) * 512 + 256 + lane*4;
#pragma unroll 2
  for (int t = 0; t < 64; t++) {
    int j = wid*64 + t;
    int4   im = mi[j];                 // broadcast ds_read_b128
    float4 wm = mw[j];
    const float4* ra = (const float4*)(p2tb + (size_t)im.x * 256) + lane;
    const float4* rb = (const float4*)(p2tb + (size_t)im.y * 256) + lane;
    const float4* rc = (const float4*)(p2tb + (size_t)im.z * 256) + lane;
    float4 A = *ra, Bv = *rb, Cv = *rc;
    float fx = wm.x*A.x + wm.y*Bv.x + wm.z*Cv.x;
    float fy = wm.x*A.y + wm.y*Bv.y + wm.z*Cv.y;
    float fz = wm.x*A.z + wm.y*Bv.z + wm.z*Cv.z;
    float fw = wm.x*A.w + wm.y*Bv.w + wm.z*Cv.w;
    uint_ lo = (uint_)f2bf(fx) | ((uint_)f2bf(fy) << 16);
    uint_ hi = (uint_)f2bf(fz) | ((uint_)f2bf(fw) << 16);
    uint2 pk; pk.x = lo; pk.y = hi;
    *(uint2*)(outb + (size_t)j * 512) = pk;
  }
}

// ---------------------------------------------------------------------------
// NT GEMM: Y[p][o] = sum_c X[p][c]*W[o][c].  X:[P][K] bf16, W:[256][K] bf16.
// R6: 256p x 256o tile (full o-width -> A fetched exactly once), 8 waves
//     (wave = 128p x 64o, acc 8x4 f32x4 = 128 VGPR), BK=32, FOUR LDS buffers
//     (4 x (A 16KB + B 16KB) = 128KB dynamic). Per-iter compute = 32 MFMA/wave
//     (~1030 cy/CU) >= HBM latency; stage(t+3) gives 3-iter prefetch lead;
//     counted vmcnt(8/4/0), never a full drain in steady state.
//     R5 failed because 128^2/BK32 = 16 MFMA/step << 900cy latency: the
//     vmcnt wait stalled every iter regardless of buffering depth.
//     LDS swizzle: linear [row][4 slots of 16B] layout has all 16 frag lanes
//     in one bank group (16-way conflict). slot ^= (row>>1)&3 applied on the
//     GLOBAL source address at stage time (global_load_lds writes linearly)
//     and on the ds_read address -> 2-way (free).
// Epilogue: per-channel sum/sumsq atomics (BN stats) + bf16 store.
__global__ __launch_bounds__(512, 2) void k_gemm(const unsigned short* __restrict__ X,
                                                 const unsigned short* __restrict__ W,
                                                 unsigned short* __restrict__ Y,
                                                 float* __restrict__ bnsum,
                                                 float* __restrict__ bnsumsq,
                                                 int K)
{
  extern __shared__ char smem[];   // 4 bufs x 32KB: [A 16KB | B 16KB]
  const int tid  = threadIdx.x;
  const int wid  = tid >> 6, lane = tid & 63;
  const int quad = lane >> 4, l16 = lane & 15;
  const int wp = wid >> 2, wo = wid & 3;          // 2 p-waves x 4 o-waves
  const size_t p0 = (size_t)blockIdx.x * 256;

  f32x4 acc[8][4] = {};   // 128 VGPR

  // --- staging map: per buffer A = 1024 granules of 16B (256 rows x 4 slots)
  // call i in {0,1}: granule g = i*512 + wid*64 + lane
  //   row = i*128 + wid*16 + (lane>>2), linear slot = lane&3
  //   swizzled source k-chunk c = (lane&3) ^ ((row>>1)&3) = (lane&3) ^ ((lane>>3)&3)
  const int grow = (wid << 4) | (lane >> 2);
  const int gcol = (((lane & 3) ^ ((lane >> 3) & 3)) << 3);   // elems (0,8,16,24)
  const unsigned short* gA0 = X + (p0 + grow)       * (size_t)K + gcol;
  const unsigned short* gA1 = X + (p0 + grow + 128) * (size_t)K + gcol;
  const unsigned short* gB0 = W + (size_t)(grow)       * K + gcol;
  const unsigned short* gB1 = W + (size_t)(grow + 128) * K + gcol;
  const int ldw = wid << 10;   // wid*1024 bytes (64 granules)

  auto stage = [&](int t) {
    char* base = smem + ((t & 3) << 15);
    const int kk = t << 5;
    async_ld16(gA0 + kk, base + ldw);
    async_ld16(gA1 + kk, base + 8192 + ldw);
    async_ld16(gB0 + kk, base + 16384 + ldw);
    async_ld16(gB1 + kk, base + 16384 + 8192 + ldw);
  };

  // --- frag-read offsets (within a buffer region), swizzled slot
  const int sw   = (quad ^ ((l16 >> 1) & 3)) << 4;
  const int aoff = ((wp << 7) + l16) * 64 + sw;   // + m*1024
  const int boff = ((wo << 6) + l16) * 64 + sw;   // + n*1024

  const int nt = K >> 5;
  stage(0); stage(1); stage(2);
  asm volatile("s_waitcnt vmcnt(8)" ::: "memory");   // buf0 landed (1,2 in flight)
  __builtin_amdgcn_s_barrier();

  for (int t = 0; t < nt; ++t) {
    const char* buf = smem + ((t & 3) << 15);
    bf16x8 af[8], bfr[4];
#pragma unroll
    for (int m = 0; m < 8; m++) af[m]  = *(const bf16x8*)(buf + aoff + m*1024);
#pragma unroll
    for (int n = 0; n < 4; n++) bfr[n] = *(const bf16x8*)(buf + 16384 + boff + n*1024);
    asm volatile("s_waitcnt lgkmcnt(0)" ::: "memory");  // my frags in regs
    __builtin_amdgcn_s_barrier();                       // all waves done reading <= buf t
    if (t + 3 < nt) stage(t + 3);                       // overwrites buf[(t-1)&3], safe
#pragma unroll
    for (int m = 0; m < 8; m++)
#pragma unroll
      for (int n = 0; n < 4; n++)
        acc[m][n] = __builtin_amdgcn_mfma_f32_16x16x32_bf16(af[m], bfr[n], acc[m][n], 0, 0, 0);
    if (t < nt - 1) {
      if (t + 3 < nt)      asm volatile("s_waitcnt vmcnt(8)" ::: "memory");  // t+1 landed
      else if (t + 2 < nt) asm volatile("s_waitcnt vmcnt(4)" ::: "memory");
      else                 asm volatile("s_waitcnt vmcnt(0)" ::: "memory");
      __builtin_amdgcn_s_barrier();
    }
  }

  // BN stats: lane sums its 32 rows (8m x 4i), reduce across quads, atomic per o
#pragma unroll
  for (int n = 0; n < 4; n++) {
    float s = 0.0f, ss = 0.0f;
#pragma unroll
    for (int m = 0; m < 8; m++)
#pragma unroll
      for (int i = 0; i < 4; i++) { float v = acc[m][n][i]; s += v; ss += v*v; }
    s  += __shfl_xor(s, 16, 64);  s  += __shfl_xor(s, 32, 64);
    ss += __shfl_xor(ss, 16, 64); ss += __shfl_xor(ss, 32, 64);
    if (quad == 0) {
      int o = (wo << 6) + (n << 4) + l16;
      atomicAdd(&bnsum[o], s);
      atomicAdd(&bnsumsq[o], ss);
    }
  }
  // store raw y (bf16). D: row(p)=quad*4+i, col(o)=l16
#pragma unroll
  for (int m = 0; m < 8; m++)
#pragma unroll
    for (int n = 0; n < 4; n++)
#pragma unroll
      for (int i = 0; i < 4; i++) {
        size_t p = p0 + (wp << 7) + (m << 4) + (quad << 2) + i;
        int    o = (wo << 6) + (n << 4) + l16;
        Y[p * 256 + o] = f2bf(acc[m][n][i]);
      }
}

// ---------------------------------------------------------------------------
// BN param: scale = g*rsqrt(var+eps), shift = be - mean*scale
__global__ void k_bn(const float* __restrict__ sum, const float* __restrict__ sumsq,
                     const float* __restrict__ g, const float* __restrict__ be,
                     float* __restrict__ scale, float* __restrict__ shift)
{
  int o = threadIdx.x;
  const float inv = 1.0f / 131072.0f;
  float m  = sum[o] * inv;
  float v  = sumsq[o] * inv - m * m;
  float sc = g[o] * rsqrtf(v + 1e-5f);
  scale[o] = sc;
  shift[o] = be[o] - m * sc;
}

// elementwise z = relu(y*scale + shift), bf16 -> bf16 (keeps GEMM2 stage-able via lds-direct)
__global__ __launch_bounds__(256) void k_z(const unsigned short* __restrict__ y,
                                           const float* __restrict__ scale,
                                           const float* __restrict__ shift,
                                           unsigned short* __restrict__ z)
{
  size_t idx = ((size_t)blockIdx.x * 256 + threadIdx.x) * 8;
  int o = (int)(idx & 255);
  u16x8 v = *(const u16x8*)(y + idx);
  u16x8 r;
#pragma unroll
  for (int i = 0; i < 8; i++) {
    float f = bf2f(v[i]);
    float t = f * scale[o + i] + shift[o + i];
    r[i] = f2bf(fmaxf(t, 0.0f));
  }
  *(u16x8*)(z + idx) = r;
}

// final: y1[p][o] bf16 -> out[b][o][n] fp32 with BN+relu, LDS transpose
__global__ __launch_bounds__(256) void k_out(const unsigned short* __restrict__ y1,
                                             const float* __restrict__ scale,
                                             const float* __restrict__ shift,
                                             float* __restrict__ out)
{
  __shared__ float t[64][65];
  const int b = blockIdx.z, o0 = blockIdx.y * 64, n0 = blockIdx.x * 64;
  const int tx = threadIdx.x & 15, ty = threadIdx.x >> 4;
  const float4 sc = *(const float4*)(scale + o0 + tx*4);
  const float4 sh = *(const float4*)(shift + o0 + tx*4);
#pragma unroll
  for (int r = 0; r < 4; r++) {
    int nl = ty + r*16;
    const unsigned short* src = y1 + ((size_t)b*NN_ + n0 + nl) * 256 + o0 + tx*4;
    ushort4 v = *(const ushort4*)src;
    t[tx*4+0][nl] = fmaxf(bf2f(v.x) * sc.x + sh.x, 0.0f);
    t[tx*4+1][nl] = fmaxf(bf2f(v.y) * sc.y + sh.y, 0.0f);
    t[tx*4+2][nl] = fmaxf(bf2f(v.z) * sc.z + sh.z, 0.0f);
    t[tx*4+3][nl] = fmaxf(bf2f(v.w) * sc.w + sh.w, 0.0f);
  }
  __syncthreads();
#pragma unroll
  for (int r = 0; r < 4; r++) {
    int ol = ty + r*16;
    float4 o4 = make_float4(t[ol][tx*4+0], t[ol][tx*4+1], t[ol][tx*4+2], t[ol][tx*4+3]);
    *(float4*)(out + ((size_t)b*256 + o0 + ol) * (size_t)NN_ + n0 + tx*4) = o4;
  }
}

// ---------------------------------------------------------------------------
extern "C" void kernel_launch(void* const* d_in, const int* in_sizes, int n_in,
                              void* d_out, int out_size, void* d_ws, size_t ws_size,
                              hipStream_t stream)
{
  const float* xyz1 = (const float*)d_in[0];
  const float* xyz2 = (const float*)d_in[1];
  const float* p1   = (const float*)d_in[2];
  const float* p2   = (const float*)d_in[3];
  const float* w0   = (const float*)d_in[4];
  const float* g0   = (const float*)d_in[6];
  const float* be0  = (const float*)d_in[7];
  const float* w1   = (const float*)d_in[8];
  const float* g1   = (const float*)d_in[10];
  const float* be1  = (const float*)d_in[11];

  // workspace layout (~192.5 MiB):
  //   [0,128Mi)    xcat [P][512] bf16      (later reused: z=[0,64Mi), y1=[64Mi,128Mi))
  //   [128,192Mi)  y0 [P][256] bf16        (p2t aliases its first 8 MiB; dead before gemm1 writes)
  //   [192Mi,...]  w0b, w1b, bn stats/params
  char* ws = (char*)d_ws;
  unsigned short* xcat = (unsigned short*)(ws);
  unsigned short* y0   = (unsigned short*)(ws + 134217728ull);
  unsigned short* zbuf = (unsigned short*)(ws);
  unsigned short* y1   = (unsigned short*)(ws + 67108864ull);
  float*          p2t  = (float*)        (ws + 134217728ull);
  unsigned short* w0b  = (unsigned short*)(ws + 201326592ull);
  unsigned short* w1b  = (unsigned short*)(ws + 201588736ull);
  float*          bn   = (float*)        (ws + 201719808ull);
  // bn: [0]sum0 [256]sumsq0 [512]sum1 [768]sumsq1 [1024]scale0 [1280]shift0 [1536]scale1 [1792]shift1

  static bool s_init = false;
  if (!s_init) {
    hipFuncSetAttribute(reinterpret_cast<const void*>(&k_gemm),
                        hipFuncAttributeMaxDynamicSharedMemorySize, 131072);
    s_init = true;
  }

  k_prep<<<512, 256, 0, stream>>>(w0, w1, w0b, w1b, bn);
  k_p2t <<<dim3(32, 8, 8),  dim3(32, 8), 0, stream>>>(p2, p2t);
  k_p1t <<<dim3(512, 8, 8), dim3(32, 8), 0, stream>>>(p1, xcat);
  k_nn  <<<512, 256, 0, stream>>>(xyz1, xyz2, p2t, xcat);
  k_gemm<<<512, 512, 131072, stream>>>(xcat, w0b, y0, bn + 0,   bn + 256, 512);
  k_bn  <<<1, 256, 0, stream>>>(bn + 0,   bn + 256, g0, be0, bn + 1024, bn + 1280);
  k_z   <<<16384, 256, 0, stream>>>(y0, bn + 1024, bn + 1280, zbuf);
  k_gemm<<<512, 512, 131072, stream>>>(zbuf, w1b, y1, bn + 512, bn + 768, 256);
  k_bn  <<<1, 256, 0, stream>>>(bn + 512, bn + 768, g1, be1, bn + 1536, bn + 1792);
  k_out <<<dim3(256, 4, 8), 256, 0, stream>>>(y1, bn + 1536, bn + 1792, (float*)d_out);
}

// Round 3
// 510.678 us; speedup vs baseline: 1.2275x; 1.0117x over previous
//
#include <hip/hip_runtime.h>
#include <stdint.h>

// Problem constants
#define BB    8
#define NN_   16384
#define SS    1024
#define PP    131072    // BB*NN_
#define CIN   512
#define CMID  256
#define COUT  256

typedef short  bf16x8 __attribute__((ext_vector_type(8)));
typedef float  f32x4  __attribute__((ext_vector_type(4)));
typedef unsigned short u16x8 __attribute__((ext_vector_type(8)));
typedef unsigned int uint_;

__device__ __forceinline__ float bf2f(unsigned short u){
  union { unsigned int i; float f; } v; v.i = ((unsigned int)u) << 16; return v.f;
}
__device__ __forceinline__ unsigned short f2bf(float f){
  union { float f; unsigned int i; } v; v.f = f;
  unsigned int r = (v.i + 0x7fffu + ((v.i >> 16) & 1u)) >> 16;  // RNE
  return (unsigned short)r;
}

// async global->LDS, 16B per lane; LDS dest must be wave-uniform base (+lane*16 implicit)
__device__ __forceinline__ void async_ld16(const void* g, void* l){
  const uint32_t __attribute__((address_space(1)))* gp =
    reinterpret_cast<const uint32_t __attribute__((address_space(1)))*>(reinterpret_cast<uintptr_t>(g));
  uint32_t __attribute__((address_space(3)))* lp =
    reinterpret_cast<uint32_t __attribute__((address_space(3)))*>(reinterpret_cast<uintptr_t>(l));
  __builtin_amdgcn_global_load_lds(gp, lp, 16, 0, 0);
}

// ---------------------------------------------------------------------------
// Prep: weights fp32->bf16, zero BN stats. (conv biases b0/b1 cancel exactly in
// training-mode BN: (y+b) - mean(y+b) == y - mean(y); variance unchanged.)
__global__ void k_prep(const float* __restrict__ w0, const float* __restrict__ w1,
                       unsigned short* __restrict__ w0b, unsigned short* __restrict__ w1b,
                       float* __restrict__ bn)
{
  int idx = blockIdx.x * 256 + threadIdx.x;   // grid 512 -> 131072 threads
  if (idx < 131072) w0b[idx] = f2bf(w0[idx]);
  if (idx < 65536)  w1b[idx] = f2bf(w1[idx]);
  if (idx < 2048)   bn[idx]  = 0.0f;          // stats + params region
}

// ---------------------------------------------------------------------------
// points2 [B][256][S] fp32 -> p2t [B][S][256] fp32 (coalesced gather rows)
__global__ void k_p2t(const float* __restrict__ p2, float* __restrict__ p2t)
{
  __shared__ float t[32][33];
  const int b = blockIdx.z, c0 = blockIdx.y * 32, s0 = blockIdx.x * 32;
  const int tx = threadIdx.x, ty = threadIdx.y;   // (32,8)
#pragma unroll
  for (int r = 0; r < 4; r++)
    t[ty + r*8][tx] = p2[((size_t)b*256 + c0 + ty + r*8) * SS + s0 + tx];
  __syncthreads();
#pragma unroll
  for (int r = 0; r < 4; r++)
    p2t[((size_t)b*SS + s0 + ty + r*8) * 256 + c0 + tx] = t[tx][ty + r*8];
}

// points1 [B][256][N] fp32 -> xcat[p][0:256] bf16  (row stride 512)
__global__ void k_p1t(const float* __restrict__ p1, unsigned short* __restrict__ xcat)
{
  __shared__ float t[32][33];
  const int b = blockIdx.z, c0 = blockIdx.y * 32, n0 = blockIdx.x * 32;
  const int tx = threadIdx.x, ty = threadIdx.y;
#pragma unroll
  for (int r = 0; r < 4; r++)
    t[ty + r*8][tx] = p1[((size_t)b*256 + c0 + ty + r*8) * (size_t)NN_ + n0 + tx];
  __syncthreads();
#pragma unroll
  for (int r = 0; r < 4; r++)
    xcat[((size_t)b*NN_ + n0 + ty + r*8) * 512 + c0 + tx] = f2bf(t[tx][ty + r*8]);
}

// ---------------------------------------------------------------------------
// 3-NN + inverse-distance interp -> xcat[p][256:512] bf16
// R7: scan was VALU-issue-bound (83% VALUBusy, ~21 instr/point). The top-6
//     insertion network min(ki, max(k_{i-1}, key)) == median(k_{i-1}, ki, key)
//     for a sorted list -> v_med3_f32. Keys move to FLOAT domain: positive
//     truncated-distance floats order identically as uint and as float, so
//     selection results are bit-identical to the uint network (same tie
//     behavior; fp64 refine unchanged). Network 11 ops -> 6 (1 min + 5 med3);
//     key pack fuses to v_and_or_b32. ~14 instr/point total.
__global__ __launch_bounds__(256) void k_nn(const float* __restrict__ xyz1,
                                            const float* __restrict__ xyz2,
                                            const float* __restrict__ p2t,
                                            unsigned short* __restrict__ xcat)
{
  __shared__ float4 pts[SS];       // 16 KB, broadcast reads
  __shared__ int4   mi[256];       // 4 KB: i0,i1,i2,pad per point
  __shared__ float4 mw[256];       // 4 KB: w0,w1,w2,pad per point
  const int blk = blockIdx.x;                  // 512 blocks
  const int b = blk & 7, nt = blk >> 3;        // XCD-aware: b == XCD id
  const int n0 = nt * 256, tid = threadIdx.x;

  for (int s = tid; s < SS; s += 256) {
    float x = xyz2[((size_t)b*3 + 0) * SS + s];
    float y = xyz2[((size_t)b*3 + 1) * SS + s];
    float z = xyz2[((size_t)b*3 + 2) * SS + s];
    pts[s] = make_float4(x, y, z, 0.0f);
  }
  __syncthreads();

  const int n = n0 + tid;
  const float qx = xyz1[((size_t)b*3 + 0) * NN_ + n];
  const float qy = xyz1[((size_t)b*3 + 1) * NN_ + n];
  const float qz = xyz1[((size_t)b*3 + 2) * NN_ + n];

  // float-domain keys: key = bits((d & 0xFFFFFC00) | s). d >= 0 finite, so
  // float ordering == uint ordering; init FLT_MAX > any real key (d < 2^9).
  const float KINIT = __uint_as_float(0x7F7FFFFFu);
  float c0 = KINIT, c1 = KINIT, c2 = KINIT, c3 = KINIT, c4 = KINIT, c5 = KINIT;
#pragma unroll 4
  for (int s = 0; s < SS; s++) {
    float4 p = pts[s];
    float dx = qx - p.x, dy = qy - p.y, dz = qz - p.z;
    float d = fmaf(dx, dx, fmaf(dy, dy, dz * dz));
    float key = __uint_as_float((__float_as_uint(d) & 0xFFFFFC00u) | (uint_)s);
    // sorted-insert, all from OLD values: n0=min(c0,key), ni=med3(c_{i-1},ci,key)
    float m0 = fminf(c0, key);
    float m1 = __builtin_amdgcn_fmed3f(c0, c1, key);
    float m2 = __builtin_amdgcn_fmed3f(c1, c2, key);
    float m3 = __builtin_amdgcn_fmed3f(c2, c3, key);
    float m4 = __builtin_amdgcn_fmed3f(c3, c4, key);
    float m5 = __builtin_amdgcn_fmed3f(c4, c5, key);
    c0 = m0; c1 = m1; c2 = m2; c3 = m3; c4 = m4; c5 = m5;
  }

  // fp64 refine: exact distances for the 6 candidates, stable sort, top-3
  const double qxd = (double)qx, qyd = (double)qy, qzd = (double)qz;
  uint_  ks[6] = { __float_as_uint(c0), __float_as_uint(c1), __float_as_uint(c2),
                   __float_as_uint(c3), __float_as_uint(c4), __float_as_uint(c5) };
  int    ii[6];
  double dd[6];
#pragma unroll
  for (int t = 0; t < 6; t++) {
    ii[t] = (int)(ks[t] & 1023u);
    float4 p = pts[ii[t]];
    double dx = qxd - (double)p.x, dy = qyd - (double)p.y, dz = qzd - (double)p.z;
    dd[t] = dx*dx + dy*dy + dz*dz;
  }
#pragma unroll
  for (int a = 1; a < 6; a++)
#pragma unroll
    for (int c = a; c > 0; c--)
      if (dd[c] < dd[c-1]) {
        double td = dd[c]; dd[c] = dd[c-1]; dd[c-1] = td;
        int    ti = ii[c]; ii[c] = ii[c-1]; ii[c-1] = ti;
      }

  double r0 = 1.0/(dd[0] + 1e-8), r1 = 1.0/(dd[1] + 1e-8), r2 = 1.0/(dd[2] + 1e-8);
  double rs = 1.0/(r0 + r1 + r2);
  mi[tid] = make_int4(ii[0], ii[1], ii[2], 0);
  mw[tid] = make_float4((float)(r0*rs), (float)(r1*rs), (float)(r2*rs), 0.0f);
  __syncthreads();

  const int wid = tid >> 6, lane = tid & 63;
  const float* p2tb = p2t + (size_t)b * SS * 256;
  unsigned short* outb = xcat + ((size_t)b*NN_ + n0) * 512 + 256 + lane*4;
#pragma unroll 2
  for (int t = 0; t < 64; t++) {
    int j = wid*64 + t;
    int4   im = mi[j];                 // broadcast ds_read_b128
    float4 wm = mw[j];
    const float4* ra = (const float4*)(p2tb + (size_t)im.x * 256) + lane;
    const float4* rb = (const float4*)(p2tb + (size_t)im.y * 256) + lane;
    const float4* rc = (const float4*)(p2tb + (size_t)im.z * 256) + lane;
    float4 A = *ra, Bv = *rb, Cv = *rc;
    float fx = wm.x*A.x + wm.y*Bv.x + wm.z*Cv.x;
    float fy = wm.x*A.y + wm.y*Bv.y + wm.z*Cv.y;
    float fz = wm.x*A.z + wm.y*Bv.z + wm.z*Cv.z;
    float fw = wm.x*A.w + wm.y*Bv.w + wm.z*Cv.w;
    uint_ lo = (uint_)f2bf(fx) | ((uint_)f2bf(fy) << 16);
    uint_ hi = (uint_)f2bf(fz) | ((uint_)f2bf(fw) << 16);
    uint2 pk; pk.x = lo; pk.y = hi;
    *(uint2*)(outb + (size_t)j * 512) = pk;
  }
}

// ---------------------------------------------------------------------------
// NT GEMM: Y[p][o] = sum_c X[p][c]*W[o][c].  X:[P][K] bf16, W:[256][K] bf16.
// R6: 256p x 256o tile (full o-width -> A fetched exactly once), 8 waves
//     (wave = 128p x 64o, acc 8x4 f32x4 = 128 VGPR), BK=32, FOUR LDS buffers
//     (4 x (A 16KB + B 16KB) = 128KB dynamic). Per-iter compute = 32 MFMA/wave
//     (~1030 cy/CU) >= HBM latency; stage(t+3) gives 3-iter prefetch lead;
//     counted vmcnt(8/4/0), never a full drain in steady state.
//     LDS swizzle: slot ^= (row>>1)&3 applied on the GLOBAL source address at
//     stage time (global_load_lds writes linearly) and on the ds_read address.
// Epilogue: per-channel sum/sumsq atomics (BN stats) + bf16 store.
__global__ __launch_bounds__(512, 2) void k_gemm(const unsigned short* __restrict__ X,
                                                 const unsigned short* __restrict__ W,
                                                 unsigned short* __restrict__ Y,
                                                 float* __restrict__ bnsum,
                                                 float* __restrict__ bnsumsq,
                                                 int K)
{
  extern __shared__ char smem[];   // 4 bufs x 32KB: [A 16KB | B 16KB]
  const int tid  = threadIdx.x;
  const int wid  = tid >> 6, lane = tid & 63;
  const int quad = lane >> 4, l16 = lane & 15;
  const int wp = wid >> 2, wo = wid & 3;          // 2 p-waves x 4 o-waves
  const size_t p0 = (size_t)blockIdx.x * 256;

  f32x4 acc[8][4] = {};   // 128 VGPR

  // --- staging map: per buffer A = 1024 granules of 16B (256 rows x 4 slots)
  const int grow = (wid << 4) | (lane >> 2);
  const int gcol = (((lane & 3) ^ ((lane >> 3) & 3)) << 3);   // elems (0,8,16,24)
  const unsigned short* gA0 = X + (p0 + grow)       * (size_t)K + gcol;
  const unsigned short* gA1 = X + (p0 + grow + 128) * (size_t)K + gcol;
  const unsigned short* gB0 = W + (size_t)(grow)       * K + gcol;
  const unsigned short* gB1 = W + (size_t)(grow + 128) * K + gcol;
  const int ldw = wid << 10;   // wid*1024 bytes (64 granules)

  auto stage = [&](int t) {
    char* base = smem + ((t & 3) << 15);
    const int kk = t << 5;
    async_ld16(gA0 + kk, base + ldw);
    async_ld16(gA1 + kk, base + 8192 + ldw);
    async_ld16(gB0 + kk, base + 16384 + ldw);
    async_ld16(gB1 + kk, base + 16384 + 8192 + ldw);
  };

  // --- frag-read offsets (within a buffer region), swizzled slot
  const int sw   = (quad ^ ((l16 >> 1) & 3)) << 4;
  const int aoff = ((wp << 7) + l16) * 64 + sw;   // + m*1024
  const int boff = ((wo << 6) + l16) * 64 + sw;   // + n*1024

  const int nt = K >> 5;
  stage(0); stage(1); stage(2);
  asm volatile("s_waitcnt vmcnt(8)" ::: "memory");   // buf0 landed (1,2 in flight)
  __builtin_amdgcn_s_barrier();

  for (int t = 0; t < nt; ++t) {
    const char* buf = smem + ((t & 3) << 15);
    bf16x8 af[8], bfr[4];
#pragma unroll
    for (int m = 0; m < 8; m++) af[m]  = *(const bf16x8*)(buf + aoff + m*1024);
#pragma unroll
    for (int n = 0; n < 4; n++) bfr[n] = *(const bf16x8*)(buf + 16384 + boff + n*1024);
    asm volatile("s_waitcnt lgkmcnt(0)" ::: "memory");  // my frags in regs
    __builtin_amdgcn_s_barrier();                       // all waves done reading <= buf t
    if (t + 3 < nt) stage(t + 3);                       // overwrites buf[(t-1)&3], safe
#pragma unroll
    for (int m = 0; m < 8; m++)
#pragma unroll
      for (int n = 0; n < 4; n++)
        acc[m][n] = __builtin_amdgcn_mfma_f32_16x16x32_bf16(af[m], bfr[n], acc[m][n], 0, 0, 0);
    if (t < nt - 1) {
      if (t + 3 < nt)      asm volatile("s_waitcnt vmcnt(8)" ::: "memory");  // t+1 landed
      else if (t + 2 < nt) asm volatile("s_waitcnt vmcnt(4)" ::: "memory");
      else                 asm volatile("s_waitcnt vmcnt(0)" ::: "memory");
      __builtin_amdgcn_s_barrier();
    }
  }

  // BN stats: lane sums its 32 rows (8m x 4i), reduce across quads, atomic per o
#pragma unroll
  for (int n = 0; n < 4; n++) {
    float s = 0.0f, ss = 0.0f;
#pragma unroll
    for (int m = 0; m < 8; m++)
#pragma unroll
      for (int i = 0; i < 4; i++) { float v = acc[m][n][i]; s += v; ss += v*v; }
    s  += __shfl_xor(s, 16, 64);  s  += __shfl_xor(s, 32, 64);
    ss += __shfl_xor(ss, 16, 64); ss += __shfl_xor(ss, 32, 64);
    if (quad == 0) {
      int o = (wo << 6) + (n << 4) + l16;
      atomicAdd(&bnsum[o], s);
      atomicAdd(&bnsumsq[o], ss);
    }
  }
  // store raw y (bf16). D: row(p)=quad*4+i, col(o)=l16
#pragma unroll
  for (int m = 0; m < 8; m++)
#pragma unroll
    for (int n = 0; n < 4; n++)
#pragma unroll
      for (int i = 0; i < 4; i++) {
        size_t p = p0 + (wp << 7) + (m << 4) + (quad << 2) + i;
        int    o = (wo << 6) + (n << 4) + l16;
        Y[p * 256 + o] = f2bf(acc[m][n][i]);
      }
}

// ---------------------------------------------------------------------------
// BN param: scale = g*rsqrt(var+eps), shift = be - mean*scale
__global__ void k_bn(const float* __restrict__ sum, const float* __restrict__ sumsq,
                     const float* __restrict__ g, const float* __restrict__ be,
                     float* __restrict__ scale, float* __restrict__ shift)
{
  int o = threadIdx.x;
  const float inv = 1.0f / 131072.0f;
  float m  = sum[o] * inv;
  float v  = sumsq[o] * inv - m * m;
  float sc = g[o] * rsqrtf(v + 1e-5f);
  scale[o] = sc;
  shift[o] = be[o] - m * sc;
}

// elementwise z = relu(y*scale + shift), bf16 -> bf16 (keeps GEMM2 stage-able via lds-direct)
__global__ __launch_bounds__(256) void k_z(const unsigned short* __restrict__ y,
                                           const float* __restrict__ scale,
                                           const float* __restrict__ shift,
                                           unsigned short* __restrict__ z)
{
  size_t idx = ((size_t)blockIdx.x * 256 + threadIdx.x) * 8;
  int o = (int)(idx & 255);
  u16x8 v = *(const u16x8*)(y + idx);
  u16x8 r;
#pragma unroll
  for (int i = 0; i < 8; i++) {
    float f = bf2f(v[i]);
    float t = f * scale[o + i] + shift[o + i];
    r[i] = f2bf(fmaxf(t, 0.0f));
  }
  *(u16x8*)(z + idx) = r;
}

// final: y1[p][o] bf16 -> out[b][o][n] fp32 with BN+relu, LDS transpose
__global__ __launch_bounds__(256) void k_out(const unsigned short* __restrict__ y1,
                                             const float* __restrict__ scale,
                                             const float* __restrict__ shift,
                                             float* __restrict__ out)
{
  __shared__ float t[64][65];
  const int b = blockIdx.z, o0 = blockIdx.y * 64, n0 = blockIdx.x * 64;
  const int tx = threadIdx.x & 15, ty = threadIdx.x >> 4;
  const float4 sc = *(const float4*)(scale + o0 + tx*4);
  const float4 sh = *(const float4*)(shift + o0 + tx*4);
#pragma unroll
  for (int r = 0; r < 4; r++) {
    int nl = ty + r*16;
    const unsigned short* src = y1 + ((size_t)b*NN_ + n0 + nl) * 256 + o0 + tx*4;
    ushort4 v = *(const ushort4*)src;
    t[tx*4+0][nl] = fmaxf(bf2f(v.x) * sc.x + sh.x, 0.0f);
    t[tx*4+1][nl] = fmaxf(bf2f(v.y) * sc.y + sh.y, 0.0f);
    t[tx*4+2][nl] = fmaxf(bf2f(v.z) * sc.z + sh.z, 0.0f);
    t[tx*4+3][nl] = fmaxf(bf2f(v.w) * sc.w + sh.w, 0.0f);
  }
  __syncthreads();
#pragma unroll
  for (int r = 0; r < 4; r++) {
    int ol = ty + r*16;
    float4 o4 = make_float4(t[ol][tx*4+0], t[ol][tx*4+1], t[ol][tx*4+2], t[ol][tx*4+3]);
    *(float4*)(out + ((size_t)b*256 + o0 + ol) * (size_t)NN_ + n0 + tx*4) = o4;
  }
}

// ---------------------------------------------------------------------------
extern "C" void kernel_launch(void* const* d_in, const int* in_sizes, int n_in,
                              void* d_out, int out_size, void* d_ws, size_t ws_size,
                              hipStream_t stream)
{
  const float* xyz1 = (const float*)d_in[0];
  const float* xyz2 = (const float*)d_in[1];
  const float* p1   = (const float*)d_in[2];
  const float* p2   = (const float*)d_in[3];
  const float* w0   = (const float*)d_in[4];
  const float* g0   = (const float*)d_in[6];
  const float* be0  = (const float*)d_in[7];
  const float* w1   = (const float*)d_in[8];
  const float* g1   = (const float*)d_in[10];
  const float* be1  = (const float*)d_in[11];

  // workspace layout (~192.5 MiB):
  //   [0,128Mi)    xcat [P][512] bf16      (later reused: z=[0,64Mi), y1=[64Mi,128Mi))
  //   [128,192Mi)  y0 [P][256] bf16        (p2t aliases its first 8 MiB; dead before gemm1 writes)
  //   [192Mi,...]  w0b, w1b, bn stats/params
  char* ws = (char*)d_ws;
  unsigned short* xcat = (unsigned short*)(ws);
  unsigned short* y0   = (unsigned short*)(ws + 134217728ull);
  unsigned short* zbuf = (unsigned short*)(ws);
  unsigned short* y1   = (unsigned short*)(ws + 67108864ull);
  float*          p2t  = (float*)        (ws + 134217728ull);
  unsigned short* w0b  = (unsigned short*)(ws + 201326592ull);
  unsigned short* w1b  = (unsigned short*)(ws + 201588736ull);
  float*          bn   = (float*)        (ws + 201719808ull);
  // bn: [0]sum0 [256]sumsq0 [512]sum1 [768]sumsq1 [1024]scale0 [1280]shift0 [1536]scale1 [1792]shift1

  static bool s_init = false;
  if (!s_init) {
    hipFuncSetAttribute(reinterpret_cast<const void*>(&k_gemm),
                        hipFuncAttributeMaxDynamicSharedMemorySize, 131072);
    s_init = true;
  }

  k_prep<<<512, 256, 0, stream>>>(w0, w1, w0b, w1b, bn);
  k_p2t <<<dim3(32, 8, 8),  dim3(32, 8), 0, stream>>>(p2, p2t);
  k_p1t <<<dim3(512, 8, 8), dim3(32, 8), 0, stream>>>(p1, xcat);
  k_nn  <<<512, 256, 0, stream>>>(xyz1, xyz2, p2t, xcat);
  k_gemm<<<512, 512, 131072, stream>>>(xcat, w0b, y0, bn + 0,   bn + 256, 512);
  k_bn  <<<1, 256, 0, stream>>>(bn + 0,   bn + 256, g0, be0, bn + 1024, bn + 1280);
  k_z   <<<16384, 256, 0, stream>>>(y0, bn + 1024, bn + 1280, zbuf);
  k_gemm<<<512, 512, 131072, stream>>>(zbuf, w1b, y1, bn + 512, bn + 768, 256);
  k_bn  <<<1, 256, 0, stream>>>(bn + 512, bn + 768, g1, be1, bn + 1536, bn + 1792);
  k_out <<<dim3(256, 4, 8), 256, 0, stream>>>(y1, bn + 1536, bn + 1792, (float*)d_out);
}